// Round 14
// baseline (510.673 us; speedup 1.0000x reference)
//
#include <hip/hip_runtime.h>

#define B_ 4
#define H_ 16
#define S_ 1024
#define D_ 64
#define NEGV -1000000000.0f

typedef __bf16 bf16x8 __attribute__((ext_vector_type(8)));
typedef __bf16 bf16x4 __attribute__((ext_vector_type(4)));
typedef float f32x4 __attribute__((ext_vector_type(4)));

#define MFMA16(A, B, C) __builtin_amdgcn_mfma_f32_16x16x32_bf16(A, B, C, 0, 0, 0)

// barrier that only orders LDS (keeps global stores/loads in flight)
__device__ __forceinline__ void bar_lds() {
  asm volatile("s_waitcnt lgkmcnt(0)" ::: "memory");
  __builtin_amdgcn_sched_barrier(0);
  __builtin_amdgcn_s_barrier();
  __builtin_amdgcn_sched_barrier(0);
}

__device__ __forceinline__ bf16x8 cvt8(const float* p) {
  float4 x = *(const float4*)p;
  float4 y = *(const float4*)(p + 4);
  bf16x8 f;
  f[0]=(__bf16)x.x; f[1]=(__bf16)x.y; f[2]=(__bf16)x.z; f[3]=(__bf16)x.w;
  f[4]=(__bf16)y.x; f[5]=(__bf16)y.y; f[6]=(__bf16)y.z; f[7]=(__bf16)y.w;
  return f;
}

// ---------------- prep: K f32 -> Kb (bf16 [B,H,S,D]), V f32 -> Vt (bf16 [B,H,D,S]) ----------------
__global__ __launch_bounds__(256) void prep_kernel(
    const float* __restrict__ K, const float* __restrict__ V,
    __bf16* __restrict__ Kb, __bf16* __restrict__ Vt)
{
  int bid = blockIdx.x;            // B*H*16 blocks, each a 64-row s-chunk
  int sc = bid & 15;
  int bh = bid >> 4;
  int tid = threadIdx.x;
  __shared__ float s_v[64][65];

  const float* Kc = K + ((size_t)bh*S_ + sc*64)*D_;
  const float* Vc = V + ((size_t)bh*S_ + sc*64)*D_;
  __bf16* Kbc = Kb + ((size_t)bh*S_ + sc*64)*D_;

  {
    const float4* src = (const float4*)Kc + tid*4;
    float4 a = src[0], b = src[1], c = src[2], d = src[3];
    bf16x8 o0, o1;
    o0[0]=(__bf16)a.x; o0[1]=(__bf16)a.y; o0[2]=(__bf16)a.z; o0[3]=(__bf16)a.w;
    o0[4]=(__bf16)b.x; o0[5]=(__bf16)b.y; o0[6]=(__bf16)b.z; o0[7]=(__bf16)b.w;
    o1[0]=(__bf16)c.x; o1[1]=(__bf16)c.y; o1[2]=(__bf16)c.z; o1[3]=(__bf16)c.w;
    o1[4]=(__bf16)d.x; o1[5]=(__bf16)d.y; o1[6]=(__bf16)d.z; o1[7]=(__bf16)d.w;
    *(bf16x8*)(Kbc + tid*16)     = o0;
    *(bf16x8*)(Kbc + tid*16 + 8) = o1;
  }
  for (int i = tid; i < 64*16; i += 256) {
    int r = i >> 4, c4 = i & 15;
    float4 v = ((const float4*)(Vc + (size_t)r*D_))[c4];
    s_v[r][c4*4+0] = v.x; s_v[r][c4*4+1] = v.y;
    s_v[r][c4*4+2] = v.z; s_v[r][c4*4+3] = v.w;
  }
  __syncthreads();
  {
    int d = tid >> 2, seg = tid & 3;
    bf16x8 o0, o1;
    #pragma unroll
    for (int j = 0; j < 8; ++j) o0[j] = (__bf16)s_v[seg*16 + j][d];
    #pragma unroll
    for (int j = 0; j < 8; ++j) o1[j] = (__bf16)s_v[seg*16 + 8 + j][d];
    __bf16* dst = Vt + ((size_t)bh*D_ + d)*S_ + sc*64 + seg*16;
    *(bf16x8*)dst = o0;
    *(bf16x8*)(dst + 8) = o1;
  }
}

// ---------------- topic: swapped MFMA + in-reg softmax -> signed bf16 tp [B,S,S] ----------------
// tp > 0: pair-unmasked, |tp| = topic_prob; tp < 0: pair-masked
__global__ __launch_bounds__(256) void topic_kernel(
    const float* __restrict__ tq, const float* __restrict__ tk,
    const int* __restrict__ mask, __bf16* __restrict__ tp)
{
  int bid0 = blockIdx.x;                 // 256 = 8 * 32
  int bid = (bid0 & 7)*32 + (bid0 >> 3);
  int qt = bid & 63, b = bid >> 6;
  int tid = threadIdx.x, wave = tid >> 6, lane = tid & 63;
  int l15 = lane & 15, lhi = lane >> 4;
  __shared__ float2 s_red[4][16];
  __shared__ __align__(16) char s_mem[4*8704];   // per-wave f32 transpose scratch [16][136]

  const int* mb = mask + b*S_;
  bf16x8 qf[2];
  #pragma unroll
  for (int dc = 0; dc < 2; ++dc)
    qf[dc] = cvt8(tq + ((size_t)b*S_ + qt*16 + l15)*D_ + dc*32 + lhi*8);
  int mq = mb[qt*16 + l15];

  f32x4 sc[16];
  #pragma unroll
  for (int kt = 0; kt < 16; ++kt) {
    int kb = wave*256 + kt*16;
    const float* kr = tk + ((size_t)b*S_ + kb + l15)*D_ + lhi*8;
    bf16x8 k0 = cvt8(kr);
    bf16x8 k1 = cvt8(kr + 32);
    f32x4 acc = {0.f,0.f,0.f,0.f};
    acc = MFMA16(k0, qf[0], acc);
    acc = MFMA16(k1, qf[1], acc);
    int4 mk = *(const int4*)(mb + kb + lhi*4);
    sc[kt][0] = (mq && mk.x) ? acc[0]*0.125f : 1.0f;
    sc[kt][1] = (mq && mk.y) ? acc[1]*0.125f : 1.0f;
    sc[kt][2] = (mq && mk.z) ? acc[2]*0.125f : 1.0f;
    sc[kt][3] = (mq && mk.w) ? acc[3]*0.125f : 1.0f;
  }
  float m = -3.4e38f;
  #pragma unroll
  for (int kt = 0; kt < 16; ++kt)
    #pragma unroll
    for (int i = 0; i < 4; ++i) m = fmaxf(m, sc[kt][i]);
  m = fmaxf(m, __shfl_xor(m, 16));
  m = fmaxf(m, __shfl_xor(m, 32));
  float sum = 0.f;
  #pragma unroll
  for (int kt = 0; kt < 16; ++kt)
    #pragma unroll
    for (int i = 0; i < 4; ++i) { sc[kt][i] = __expf(sc[kt][i] - m); sum += sc[kt][i]; }
  sum += __shfl_xor(sum, 16);
  sum += __shfl_xor(sum, 32);
  if (lane < 16) s_red[wave][l15] = make_float2(m, sum);
  bar_lds();
  float M = -3.4e38f;
  #pragma unroll
  for (int w = 0; w < 4; ++w) M = fmaxf(M, s_red[w][l15].x);
  float Z = 0.f;
  #pragma unroll
  for (int w = 0; w < 4; ++w) Z += s_red[w][l15].y * __expf(s_red[w][l15].x - M);
  float scale = __expf(m - M) / Z;

  #pragma unroll
  for (int kt = 0; kt < 16; ++kt) {
    int kb = wave*256 + kt*16;
    int4 mk = *(const int4*)(mb + kb + lhi*4);
    sc[kt][0] *= scale; if (!(mq && mk.x)) sc[kt][0] = -sc[kt][0];
    sc[kt][1] *= scale; if (!(mq && mk.y)) sc[kt][1] = -sc[kt][1];
    sc[kt][2] *= scale; if (!(mq && mk.z)) sc[kt][2] = -sc[kt][2];
    sc[kt][3] *= scale; if (!(mq && mk.w)) sc[kt][3] = -sc[kt][3];
  }

  // transpose via wave-private LDS -> coalesced bf16 stores
  float* xw = (float*)s_mem + wave*2176;
  __bf16* tpw = tp + ((size_t)b*S_ + qt*16)*S_ + wave*256;
  #pragma unroll
  for (int h = 0; h < 2; ++h) {
    #pragma unroll
    for (int j = 0; j < 8; ++j)
      *(f32x4*)(xw + l15*136 + j*16 + lhi*4) = sc[h*8 + j];
    bar_lds();
    #pragma unroll
    for (int rr = 0; rr < 8; ++rr) {
      int r = rr*2 + (lane >> 5);
      f32x4 a = *(f32x4*)(xw + r*136 + (lane & 31)*4);
      bf16x4 o;
      o[0]=(__bf16)a[0]; o[1]=(__bf16)a[1]; o[2]=(__bf16)a[2]; o[3]=(__bf16)a[3];
      *(bf16x4*)(tpw + (size_t)r*S_ + h*128 + (lane & 31)*4) = o;
    }
    bar_lds();
  }
}

// ---------------- attn: QK^T (depth-3 ring, online m/Z) -> emit-only softmax -> PV (ring) ----------------
__global__ __launch_bounds__(256) void attn_kernel(
    const float* __restrict__ Q, const __bf16* __restrict__ Kb,
    const __bf16* __restrict__ Vt, const __bf16* __restrict__ tp,
    float* __restrict__ out, float* __restrict__ pa)
{
  int bid0 = blockIdx.x;                 // 4096 = 8 * 512
  int bid = (bid0 & 7)*512 + (bid0 >> 3);
  int qt = bid & 63;
  int h  = (bid >> 6) & 15;
  int b  = bid >> 10;
  int tid = threadIdx.x, wave = tid >> 6, lane = tid & 63;
  int l15 = lane & 15, lhi = lane >> 4;

  // scores/P bf16 [16][1024], XOR-swizzled: byte = row*2048 + ((col*2) ^ ((row&7)<<4))
  __shared__ __align__(16) char s_p[16*2048];
  __shared__ float2 s_red[4][16];        // per-wave per-row (m, Z)

  size_t bh = (size_t)b*H_ + h;
  const __bf16* Kbh = Kb + bh*S_*D_;
  const __bf16* tpb = tp + ((size_t)b*S_ + qt*16)*S_;   // [16 rows][1024]

  // Q fragments (A): row = l15 (q), k(d) = dc*32 + lhi*8 + i
  bf16x8 qf[2];
  #pragma unroll
  for (int dc = 0; dc < 2; ++dc)
    qf[dc] = cvt8(Q + (bh*S_ + qt*16 + l15)*D_ + dc*32 + lhi*8);

  // ---- QK^T with depth-3 K ring + online per-row (m,Z) in registers ----
  // lane holds rows lhi*4+i, col kcol per kt -> per-lane partial (m,Z) for its 4 rows
  f32x4 pm = {-3.4e38f,-3.4e38f,-3.4e38f,-3.4e38f};
  f32x4 pz = {0.f,0.f,0.f,0.f};
  bf16x8 rk0[3], rk1[3];
  #pragma unroll
  for (int p = 0; p < 2; ++p) {
    const __bf16* kr = Kbh + (size_t)(wave*256 + p*16 + l15)*D_ + lhi*8;
    rk0[p] = *(const bf16x8*)kr;
    rk1[p] = *(const bf16x8*)(kr + 32);
  }
  for (int kt = 0; kt < 16; ++kt) {
    const int cur = kt % 3;
    if (kt + 2 < 16) {
      const int nxt = (kt + 2) % 3;
      const __bf16* kr = Kbh + (size_t)(wave*256 + (kt+2)*16 + l15)*D_ + lhi*8;
      rk0[nxt] = *(const bf16x8*)kr;
      rk1[nxt] = *(const bf16x8*)(kr + 32);
    }
    int kcol = wave*256 + kt*16 + l15;
    f32x4 acc = {0.f,0.f,0.f,0.f};
    acc = MFMA16(qf[0], rk0[cur], acc);
    acc = MFMA16(qf[1], rk1[cur], acc);
    #pragma unroll
    for (int i = 0; i < 4; ++i) {
      int row = lhi*4 + i;
      float t = (float)tpb[(size_t)row*S_ + kcol];
      float s = (t > 0.f) ? acc[i]*0.125f*t : NEGV*(-t);
      *(__bf16*)(s_p + row*2048 + ((kcol*2) ^ ((row&7)<<4))) = (__bf16)s;
      float sB = (float)(__bf16)s;         // bf16-rounded (matches LDS value)
      float nm = fmaxf(pm[i], sB);
      pz[i] = pz[i]*__expf(pm[i]-nm) + __expf(sB-nm);
      pm[i] = nm;
    }
  }
  // fold across the 16 lanes sharing each row group (xor 1,2,4,8)
  #pragma unroll
  for (int o = 1; o <= 8; o <<= 1) {
    #pragma unroll
    for (int i = 0; i < 4; ++i) {
      float mo = __shfl_xor(pm[i], o);
      float zo = __shfl_xor(pz[i], o);
      float nm = fmaxf(pm[i], mo);
      pz[i] = pz[i]*__expf(pm[i]-nm) + zo*__expf(mo-nm);
      pm[i] = nm;
    }
  }
  // lane l15==0 of each lhi group holds rows lhi*4..lhi*4+3 partials for this wave's k-range
  if (l15 == 0) {
    #pragma unroll
    for (int i = 0; i < 4; ++i)
      s_red[wave][lhi*4 + i] = make_float2(pm[i], pz[i]);
  }
  bar_lds();

  // ---- emit-only softmax: wave owns rows [wave*4, wave*4+4) ----
  #pragma unroll
  for (int r = 0; r < 4; ++r) {
    int row = wave*4 + r;
    // combine the 4 wave-partials for this row (tiny serial chain, no shuffles)
    float2 a0 = s_red[0][row], a1 = s_red[1][row], a2 = s_red[2][row], a3 = s_red[3][row];
    float M = fmaxf(fmaxf(a0.x, a1.x), fmaxf(a2.x, a3.x));
    float Z = a0.y*__expf(a0.x-M) + a1.y*__expf(a1.x-M)
            + a2.y*__expf(a2.x-M) + a3.y*__expf(a3.x-M);
    float inv = 1.0f / Z;
    int swz = (row & 7) << 4;
    float* par = pa + (bh*S_ + qt*16 + row)*S_;
    #pragma unroll
    for (int j = 0; j < 16; ++j) {
      float sv = (float)*(const __bf16*)(s_p + row*2048 + (((lane + j*64)*2) ^ swz));
      float pv = __expf(sv - M) * inv;
      par[lane + j*64] = pv;                // coalesced 256B/instr
      *(__bf16*)(s_p + row*2048 + (((lane + j*64)*2) ^ swz)) = (__bf16)pv;
    }
  }
  bar_lds();

  // ---- PV: wave w covers d in [w*16, w*16+16); A from LDS, B from global Vt (depth-3 ring) ----
  const __bf16* Vh = Vt + (bh*D_ + wave*16 + l15)*S_ + lhi*8;
  bf16x8 rv[3];
  #pragma unroll
  for (int p = 0; p < 2; ++p) rv[p] = *(const bf16x8*)(Vh + p*32);
  f32x4 oacc = {0.f,0.f,0.f,0.f};
  for (int ks = 0; ks < 32; ++ks) {
    if (ks + 2 < 32) rv[(ks+2)%3] = *(const bf16x8*)(Vh + (ks+2)*32);
    bf16x8 a = *(const bf16x8*)(s_p + l15*2048 + ((ks*64 + lhi*16) ^ ((l15 & 7) << 4)));
    oacc = MFMA16(a, rv[ks%3], oacc);
  }
  #pragma unroll
  for (int i = 0; i < 4; ++i)
    out[(bh*S_ + qt*16 + lhi*4 + i)*D_ + wave*16 + l15] = oacc[i];
}

extern "C" void kernel_launch(void* const* d_in, const int* in_sizes, int n_in,
                              void* d_out, int out_size, void* d_ws, size_t ws_size,
                              hipStream_t stream) {
  const float* Q    = (const float*)d_in[0];
  const float* K    = (const float*)d_in[1];
  const float* V    = (const float*)d_in[2];
  const int*   mask = (const int*)d_in[4];
  const float* tq   = (const float*)d_in[5];
  const float* tk   = (const float*)d_in[6];

  // ws layout: tp bf16 [B,S,S] = 8MB | Kb bf16 [B,H,S,D] = 8MB | Vt bf16 [B,H,D,S] = 8MB
  __bf16* tp = (__bf16*)d_ws;
  __bf16* Kb = tp + (size_t)B_*S_*S_;
  __bf16* Vt = Kb + (size_t)B_*H_*S_*D_;

  float* outp = (float*)d_out;                      // [B,H,S,D]
  float* pa   = outp + (size_t)B_*H_*S_*D_;         // [B,H,S,S]

  prep_kernel <<<B_*H_*16, 256, 0, stream>>>(K, V, Kb, Vt);
  topic_kernel<<<B_*64,    256, 0, stream>>>(tq, tk, mask, tp);
  attn_kernel <<<B_*H_*64, 256, 0, stream>>>(Q, Kb, Vt, tp, outp, pa);
}

// Round 15
// 195.880 us; speedup vs baseline: 2.6071x; 2.6071x over previous
//
#include <hip/hip_runtime.h>

#define B_ 4
#define H_ 16
#define S_ 1024
#define D_ 64
#define NEGV -1000000000.0f

typedef __bf16 bf16x8 __attribute__((ext_vector_type(8)));
typedef __bf16 bf16x4 __attribute__((ext_vector_type(4)));
typedef float f32x4 __attribute__((ext_vector_type(4)));

#define MFMA16(A, B, C) __builtin_amdgcn_mfma_f32_16x16x32_bf16(A, B, C, 0, 0, 0)

// barrier that only orders LDS (keeps global stores/loads in flight)
__device__ __forceinline__ void bar_lds() {
  asm volatile("s_waitcnt lgkmcnt(0)" ::: "memory");
  __builtin_amdgcn_sched_barrier(0);
  __builtin_amdgcn_s_barrier();
  __builtin_amdgcn_sched_barrier(0);
}

__device__ __forceinline__ bf16x8 cvt8(const float* p) {
  float4 x = *(const float4*)p;
  float4 y = *(const float4*)(p + 4);
  bf16x8 f;
  f[0]=(__bf16)x.x; f[1]=(__bf16)x.y; f[2]=(__bf16)x.z; f[3]=(__bf16)x.w;
  f[4]=(__bf16)y.x; f[5]=(__bf16)y.y; f[6]=(__bf16)y.z; f[7]=(__bf16)y.w;
  return f;
}

// ---------------- fused prep (1024 blocks) + topic (256 blocks) ----------------
// prep: K f32 -> Kb bf16 [B,H,S,D]; V f32 -> Vt bf16 [B,H,D,S]
// topic: swapped MFMA + in-reg softmax -> signed bf16 tp [B,S,S]
//        (tp > 0: unmasked, |tp| = prob; tp < 0: masked)
__global__ __launch_bounds__(256) void pre_kernel(
    const float* __restrict__ K, const float* __restrict__ V,
    const float* __restrict__ tq, const float* __restrict__ tk,
    const int* __restrict__ mask,
    __bf16* __restrict__ Kb, __bf16* __restrict__ Vt, __bf16* __restrict__ tp)
{
  __shared__ __align__(16) char s_all[35328];   // union: prep s_v | topic s_red+s_mem
  int tid = threadIdx.x;

  if (blockIdx.x < B_*H_*16) {
    // ================= prep path =================
    int bid = blockIdx.x;
    int sc = bid & 15;
    int bh = bid >> 4;
    float* s_v = (float*)s_all;                 // [64][65]

    const float* Kc = K + ((size_t)bh*S_ + sc*64)*D_;
    const float* Vc = V + ((size_t)bh*S_ + sc*64)*D_;
    __bf16* Kbc = Kb + ((size_t)bh*S_ + sc*64)*D_;

    {
      const float4* src = (const float4*)Kc + tid*4;
      float4 a = src[0], b = src[1], c = src[2], d = src[3];
      bf16x8 o0, o1;
      o0[0]=(__bf16)a.x; o0[1]=(__bf16)a.y; o0[2]=(__bf16)a.z; o0[3]=(__bf16)a.w;
      o0[4]=(__bf16)b.x; o0[5]=(__bf16)b.y; o0[6]=(__bf16)b.z; o0[7]=(__bf16)b.w;
      o1[0]=(__bf16)c.x; o1[1]=(__bf16)c.y; o1[2]=(__bf16)c.z; o1[3]=(__bf16)c.w;
      o1[4]=(__bf16)d.x; o1[5]=(__bf16)d.y; o1[6]=(__bf16)d.z; o1[7]=(__bf16)d.w;
      *(bf16x8*)(Kbc + tid*16)     = o0;
      *(bf16x8*)(Kbc + tid*16 + 8) = o1;
    }
    for (int i = tid; i < 64*16; i += 256) {
      int r = i >> 4, c4 = i & 15;
      float4 v = ((const float4*)(Vc + (size_t)r*D_))[c4];
      s_v[r*65 + c4*4+0] = v.x; s_v[r*65 + c4*4+1] = v.y;
      s_v[r*65 + c4*4+2] = v.z; s_v[r*65 + c4*4+3] = v.w;
    }
    __syncthreads();
    {
      int d = tid >> 2, seg = tid & 3;
      bf16x8 o0, o1;
      #pragma unroll
      for (int j = 0; j < 8; ++j) o0[j] = (__bf16)s_v[(seg*16 + j)*65 + d];
      #pragma unroll
      for (int j = 0; j < 8; ++j) o1[j] = (__bf16)s_v[(seg*16 + 8 + j)*65 + d];
      __bf16* dst = Vt + ((size_t)bh*D_ + d)*S_ + sc*64 + seg*16;
      *(bf16x8*)dst = o0;
      *(bf16x8*)(dst + 8) = o1;
    }
    return;
  }

  // ================= topic path =================
  int bid0 = blockIdx.x - B_*H_*16;             // 0..255 ; 256 = 8 * 32
  int bid = (bid0 & 7)*32 + (bid0 >> 3);
  int qt = bid & 63, b = bid >> 6;
  int wave = tid >> 6, lane = tid & 63;
  int l15 = lane & 15, lhi = lane >> 4;
  float2* s_red = (float2*)s_all;               // [4][16]
  char* s_mem = s_all + 512;                    // 4 x [16][136] f32

  const int* mb = mask + b*S_;
  bf16x8 qf[2];
  #pragma unroll
  for (int dc = 0; dc < 2; ++dc)
    qf[dc] = cvt8(tq + ((size_t)b*S_ + qt*16 + l15)*D_ + dc*32 + lhi*8);
  int mq = mb[qt*16 + l15];

  f32x4 sc[16];
  #pragma unroll
  for (int kt = 0; kt < 16; ++kt) {
    int kb = wave*256 + kt*16;
    const float* kr = tk + ((size_t)b*S_ + kb + l15)*D_ + lhi*8;
    bf16x8 k0 = cvt8(kr);
    bf16x8 k1 = cvt8(kr + 32);
    f32x4 acc = {0.f,0.f,0.f,0.f};
    acc = MFMA16(k0, qf[0], acc);
    acc = MFMA16(k1, qf[1], acc);
    int4 mk = *(const int4*)(mb + kb + lhi*4);
    sc[kt][0] = (mq && mk.x) ? acc[0]*0.125f : 1.0f;
    sc[kt][1] = (mq && mk.y) ? acc[1]*0.125f : 1.0f;
    sc[kt][2] = (mq && mk.z) ? acc[2]*0.125f : 1.0f;
    sc[kt][3] = (mq && mk.w) ? acc[3]*0.125f : 1.0f;
  }
  float m = -3.4e38f;
  #pragma unroll
  for (int kt = 0; kt < 16; ++kt)
    #pragma unroll
    for (int i = 0; i < 4; ++i) m = fmaxf(m, sc[kt][i]);
  m = fmaxf(m, __shfl_xor(m, 16));
  m = fmaxf(m, __shfl_xor(m, 32));
  float sum = 0.f;
  #pragma unroll
  for (int kt = 0; kt < 16; ++kt)
    #pragma unroll
    for (int i = 0; i < 4; ++i) { sc[kt][i] = __expf(sc[kt][i] - m); sum += sc[kt][i]; }
  sum += __shfl_xor(sum, 16);
  sum += __shfl_xor(sum, 32);
  if (lane < 16) s_red[wave*16 + l15] = make_float2(m, sum);
  bar_lds();
  float M = -3.4e38f;
  #pragma unroll
  for (int w = 0; w < 4; ++w) M = fmaxf(M, s_red[w*16 + l15].x);
  float Z = 0.f;
  #pragma unroll
  for (int w = 0; w < 4; ++w) Z += s_red[w*16 + l15].y * __expf(s_red[w*16 + l15].x - M);
  float scale = __expf(m - M) / Z;

  #pragma unroll
  for (int kt = 0; kt < 16; ++kt) {
    int kb = wave*256 + kt*16;
    int4 mk = *(const int4*)(mb + kb + lhi*4);
    sc[kt][0] *= scale; if (!(mq && mk.x)) sc[kt][0] = -sc[kt][0];
    sc[kt][1] *= scale; if (!(mq && mk.y)) sc[kt][1] = -sc[kt][1];
    sc[kt][2] *= scale; if (!(mq && mk.z)) sc[kt][2] = -sc[kt][2];
    sc[kt][3] *= scale; if (!(mq && mk.w)) sc[kt][3] = -sc[kt][3];
  }

  // transpose via wave-private LDS -> coalesced bf16 stores
  float* xw = (float*)s_mem + wave*2176;
  __bf16* tpw = tp + ((size_t)b*S_ + qt*16)*S_ + wave*256;
  #pragma unroll
  for (int h = 0; h < 2; ++h) {
    #pragma unroll
    for (int j = 0; j < 8; ++j)
      *(f32x4*)(xw + l15*136 + j*16 + lhi*4) = sc[h*8 + j];
    bar_lds();
    #pragma unroll
    for (int rr = 0; rr < 8; ++rr) {
      int r = rr*2 + (lane >> 5);
      f32x4 a = *(f32x4*)(xw + r*136 + (lane & 31)*4);
      bf16x4 o;
      o[0]=(__bf16)a[0]; o[1]=(__bf16)a[1]; o[2]=(__bf16)a[2]; o[3]=(__bf16)a[3];
      *(bf16x4*)(tpw + (size_t)r*S_ + h*128 + (lane & 31)*4) = o;
    }
    bar_lds();
  }
}

// ---------------- attn (R13, unchanged): non-swapped QK^T -> swizzled LDS scores ----------------
// -> per-row softmax from LDS -> coalesced pa -> P bf16 LDS -> PV with global Vt
__global__ __launch_bounds__(256) void attn_kernel(
    const float* __restrict__ Q, const __bf16* __restrict__ Kb,
    const __bf16* __restrict__ Vt, const __bf16* __restrict__ tp,
    float* __restrict__ out, float* __restrict__ pa)
{
  int bid0 = blockIdx.x;                 // 4096 = 8 * 512
  int bid = (bid0 & 7)*512 + (bid0 >> 3);
  int qt = bid & 63;
  int h  = (bid >> 6) & 15;
  int b  = bid >> 10;
  int tid = threadIdx.x, wave = tid >> 6, lane = tid & 63;
  int l15 = lane & 15, lhi = lane >> 4;

  // scores/P bf16 [16][1024], XOR-swizzled: byte = row*2048 + ((col*2) ^ ((row&7)<<4))
  __shared__ __align__(16) char s_p[16*2048];

  size_t bh = (size_t)b*H_ + h;
  const __bf16* Kbh = Kb + bh*S_*D_;
  const __bf16* tpb = tp + ((size_t)b*S_ + qt*16)*S_;   // [16 rows][1024]

  // Q fragments (A): row = l15 (q), k(d) = dc*32 + lhi*8 + i
  bf16x8 qf[2];
  #pragma unroll
  for (int dc = 0; dc < 2; ++dc)
    qf[dc] = cvt8(Q + (bh*S_ + qt*16 + l15)*D_ + dc*32 + lhi*8);

  // ---- QK^T: wave w covers k in [w*256, w*256+256) ----
  for (int kt = 0; kt < 16; ++kt) {
    int kb = wave*256 + kt*16;
    int kcol = kb + l15;
    const __bf16* kr = Kbh + (size_t)kcol*D_ + lhi*8;
    bf16x8 k0 = *(const bf16x8*)kr;
    bf16x8 k1 = *(const bf16x8*)(kr + 32);
    f32x4 acc = {0.f,0.f,0.f,0.f};
    acc = MFMA16(qf[0], k0, acc);
    acc = MFMA16(qf[1], k1, acc);
    #pragma unroll
    for (int i = 0; i < 4; ++i) {
      int row = lhi*4 + i;                  // q within tile
      float t = (float)tpb[(size_t)row*S_ + kcol];
      float s = (t > 0.f) ? acc[i]*0.125f*t : NEGV*(-t);
      *(__bf16*)(s_p + row*2048 + ((kcol*2) ^ ((row&7)<<4))) = (__bf16)s;
    }
  }
  bar_lds();

  // ---- softmax: wave owns rows [wave*4, wave*4+4); pa written inline (coalesced) ----
  #pragma unroll
  for (int r = 0; r < 4; ++r) {
    int row = wave*4 + r;
    int swz = (row & 7) << 4;
    float sv[16]; float m = -3.4e38f;
    #pragma unroll
    for (int j = 0; j < 16; ++j) {
      sv[j] = (float)*(const __bf16*)(s_p + row*2048 + (((lane + j*64)*2) ^ swz));
      m = fmaxf(m, sv[j]);
    }
    #pragma unroll
    for (int o = 32; o >= 1; o >>= 1) m = fmaxf(m, __shfl_xor(m, o));
    float ev[16]; float sum = 0.f;
    #pragma unroll
    for (int j = 0; j < 16; ++j) { ev[j] = __expf(sv[j]-m); sum += ev[j]; }
    #pragma unroll
    for (int o = 32; o >= 1; o >>= 1) sum += __shfl_xor(sum, o);
    float inv = 1.0f/sum;
    float* par = pa + (bh*S_ + qt*16 + row)*S_;
    #pragma unroll
    for (int j = 0; j < 16; ++j) {
      float pv = ev[j]*inv;
      par[lane + j*64] = pv;                // coalesced 256B/instr
      *(__bf16*)(s_p + row*2048 + (((lane + j*64)*2) ^ swz)) = (__bf16)pv;
    }
  }
  bar_lds();

  // ---- PV: wave w covers d in [w*16, w*16+16); A from LDS, B from global Vt ----
  const __bf16* Vh = Vt + (bh*D_ + wave*16 + l15)*S_ + lhi*8;
  f32x4 oacc = {0.f,0.f,0.f,0.f};
  #pragma unroll 8
  for (int ks = 0; ks < 32; ++ks) {
    bf16x8 a  = *(const bf16x8*)(s_p + l15*2048 + ((ks*64 + lhi*16) ^ ((l15 & 7) << 4)));
    bf16x8 bv = *(const bf16x8*)(Vh + ks*32);
    oacc = MFMA16(a, bv, oacc);
  }
  #pragma unroll
  for (int i = 0; i < 4; ++i)
    out[(bh*S_ + qt*16 + lhi*4 + i)*D_ + wave*16 + l15] = oacc[i];
}

extern "C" void kernel_launch(void* const* d_in, const int* in_sizes, int n_in,
                              void* d_out, int out_size, void* d_ws, size_t ws_size,
                              hipStream_t stream) {
  const float* Q    = (const float*)d_in[0];
  const float* K    = (const float*)d_in[1];
  const float* V    = (const float*)d_in[2];
  const int*   mask = (const int*)d_in[4];
  const float* tq   = (const float*)d_in[5];
  const float* tk   = (const float*)d_in[6];

  // ws layout: tp bf16 [B,S,S] = 8MB | Kb bf16 [B,H,S,D] = 8MB | Vt bf16 [B,H,D,S] = 8MB
  __bf16* tp = (__bf16*)d_ws;
  __bf16* Kb = tp + (size_t)B_*S_*S_;
  __bf16* Vt = Kb + (size_t)B_*H_*S_*D_;

  float* outp = (float*)d_out;                      // [B,H,S,D]
  float* pa   = outp + (size_t)B_*H_*S_*D_;         // [B,H,S,S]

  pre_kernel <<<B_*H_*16 + B_*64, 256, 0, stream>>>(K, V, tq, tk, mask, Kb, Vt, tp);
  attn_kernel<<<B_*H_*64, 256, 0, stream>>>(Q, Kb, Vt, tp, outp, pa);
}

// Round 16
// 182.708 us; speedup vs baseline: 2.7950x; 1.0721x over previous
//
#include <hip/hip_runtime.h>

#define B_ 4
#define H_ 16
#define S_ 1024
#define D_ 64
#define NEGV -1000000000.0f

typedef __bf16 bf16x8 __attribute__((ext_vector_type(8)));
typedef __bf16 bf16x4 __attribute__((ext_vector_type(4)));
typedef float f32x4 __attribute__((ext_vector_type(4)));

#define MFMA16(A, B, C) __builtin_amdgcn_mfma_f32_16x16x32_bf16(A, B, C, 0, 0, 0)

// barrier that only orders LDS (keeps global stores/loads in flight)
__device__ __forceinline__ void bar_lds() {
  asm volatile("s_waitcnt lgkmcnt(0)" ::: "memory");
  __builtin_amdgcn_sched_barrier(0);
  __builtin_amdgcn_s_barrier();
  __builtin_amdgcn_sched_barrier(0);
}

__device__ __forceinline__ bf16x8 cvt8(const float* p) {
  float4 x = *(const float4*)p;
  float4 y = *(const float4*)(p + 4);
  bf16x8 f;
  f[0]=(__bf16)x.x; f[1]=(__bf16)x.y; f[2]=(__bf16)x.z; f[3]=(__bf16)x.w;
  f[4]=(__bf16)y.x; f[5]=(__bf16)y.y; f[6]=(__bf16)y.z; f[7]=(__bf16)y.w;
  return f;
}

// ---------------- prep: K f32 -> Kb (bf16 [B,H,S,D]), V f32 -> Vt (bf16 [B,H,D,S]) ----------------
__global__ __launch_bounds__(256) void prep_kernel(
    const float* __restrict__ K, const float* __restrict__ V,
    __bf16* __restrict__ Kb, __bf16* __restrict__ Vt)
{
  int bid = blockIdx.x;            // B*H*16 blocks, each a 64-row s-chunk
  int sc = bid & 15;
  int bh = bid >> 4;
  int tid = threadIdx.x;
  __shared__ float s_v[64][65];

  const float* Kc = K + ((size_t)bh*S_ + sc*64)*D_;
  const float* Vc = V + ((size_t)bh*S_ + sc*64)*D_;
  __bf16* Kbc = Kb + ((size_t)bh*S_ + sc*64)*D_;

  {
    const float4* src = (const float4*)Kc + tid*4;
    float4 a = src[0], b = src[1], c = src[2], d = src[3];
    bf16x8 o0, o1;
    o0[0]=(__bf16)a.x; o0[1]=(__bf16)a.y; o0[2]=(__bf16)a.z; o0[3]=(__bf16)a.w;
    o0[4]=(__bf16)b.x; o0[5]=(__bf16)b.y; o0[6]=(__bf16)b.z; o0[7]=(__bf16)b.w;
    o1[0]=(__bf16)c.x; o1[1]=(__bf16)c.y; o1[2]=(__bf16)c.z; o1[3]=(__bf16)c.w;
    o1[4]=(__bf16)d.x; o1[5]=(__bf16)d.y; o1[6]=(__bf16)d.z; o1[7]=(__bf16)d.w;
    *(bf16x8*)(Kbc + tid*16)     = o0;
    *(bf16x8*)(Kbc + tid*16 + 8) = o1;
  }
  for (int i = tid; i < 64*16; i += 256) {
    int r = i >> 4, c4 = i & 15;
    float4 v = ((const float4*)(Vc + (size_t)r*D_))[c4];
    s_v[r][c4*4+0] = v.x; s_v[r][c4*4+1] = v.y;
    s_v[r][c4*4+2] = v.z; s_v[r][c4*4+3] = v.w;
  }
  __syncthreads();
  {
    int d = tid >> 2, seg = tid & 3;
    bf16x8 o0, o1;
    #pragma unroll
    for (int j = 0; j < 8; ++j) o0[j] = (__bf16)s_v[seg*16 + j][d];
    #pragma unroll
    for (int j = 0; j < 8; ++j) o1[j] = (__bf16)s_v[seg*16 + 8 + j][d];
    __bf16* dst = Vt + ((size_t)bh*D_ + d)*S_ + sc*64 + seg*16;
    *(bf16x8*)dst = o0;
    *(bf16x8*)(dst + 8) = o1;
  }
}

// ---------------- topic: swapped MFMA + in-reg softmax -> signed bf16 tp [B,S,S] ----------------
// tp > 0: pair-unmasked, |tp| = topic_prob; tp < 0: pair-masked
__global__ __launch_bounds__(256) void topic_kernel(
    const float* __restrict__ tq, const float* __restrict__ tk,
    const int* __restrict__ mask, __bf16* __restrict__ tp)
{
  int bid0 = blockIdx.x;                 // 256 = 8 * 32
  int bid = (bid0 & 7)*32 + (bid0 >> 3);
  int qt = bid & 63, b = bid >> 6;
  int tid = threadIdx.x, wave = tid >> 6, lane = tid & 63;
  int l15 = lane & 15, lhi = lane >> 4;
  __shared__ float2 s_red[4][16];
  __shared__ __align__(16) char s_mem[4*8704];   // per-wave f32 transpose scratch [16][136]

  const int* mb = mask + b*S_;
  bf16x8 qf[2];
  #pragma unroll
  for (int dc = 0; dc < 2; ++dc)
    qf[dc] = cvt8(tq + ((size_t)b*S_ + qt*16 + l15)*D_ + dc*32 + lhi*8);
  int mq = mb[qt*16 + l15];

  f32x4 sc[16];
  #pragma unroll
  for (int kt = 0; kt < 16; ++kt) {
    int kb = wave*256 + kt*16;
    const float* kr = tk + ((size_t)b*S_ + kb + l15)*D_ + lhi*8;
    bf16x8 k0 = cvt8(kr);
    bf16x8 k1 = cvt8(kr + 32);
    f32x4 acc = {0.f,0.f,0.f,0.f};
    acc = MFMA16(k0, qf[0], acc);
    acc = MFMA16(k1, qf[1], acc);
    int4 mk = *(const int4*)(mb + kb + lhi*4);
    sc[kt][0] = (mq && mk.x) ? acc[0]*0.125f : 1.0f;
    sc[kt][1] = (mq && mk.y) ? acc[1]*0.125f : 1.0f;
    sc[kt][2] = (mq && mk.z) ? acc[2]*0.125f : 1.0f;
    sc[kt][3] = (mq && mk.w) ? acc[3]*0.125f : 1.0f;
  }
  float m = -3.4e38f;
  #pragma unroll
  for (int kt = 0; kt < 16; ++kt)
    #pragma unroll
    for (int i = 0; i < 4; ++i) m = fmaxf(m, sc[kt][i]);
  m = fmaxf(m, __shfl_xor(m, 16));
  m = fmaxf(m, __shfl_xor(m, 32));
  float sum = 0.f;
  #pragma unroll
  for (int kt = 0; kt < 16; ++kt)
    #pragma unroll
    for (int i = 0; i < 4; ++i) { sc[kt][i] = __expf(sc[kt][i] - m); sum += sc[kt][i]; }
  sum += __shfl_xor(sum, 16);
  sum += __shfl_xor(sum, 32);
  if (lane < 16) s_red[wave][l15] = make_float2(m, sum);
  bar_lds();
  float M = -3.4e38f;
  #pragma unroll
  for (int w = 0; w < 4; ++w) M = fmaxf(M, s_red[w][l15].x);
  float Z = 0.f;
  #pragma unroll
  for (int w = 0; w < 4; ++w) Z += s_red[w][l15].y * __expf(s_red[w][l15].x - M);
  float scale = __expf(m - M) / Z;

  #pragma unroll
  for (int kt = 0; kt < 16; ++kt) {
    int kb = wave*256 + kt*16;
    int4 mk = *(const int4*)(mb + kb + lhi*4);
    sc[kt][0] *= scale; if (!(mq && mk.x)) sc[kt][0] = -sc[kt][0];
    sc[kt][1] *= scale; if (!(mq && mk.y)) sc[kt][1] = -sc[kt][1];
    sc[kt][2] *= scale; if (!(mq && mk.z)) sc[kt][2] = -sc[kt][2];
    sc[kt][3] *= scale; if (!(mq && mk.w)) sc[kt][3] = -sc[kt][3];
  }

  // transpose via wave-private LDS -> coalesced bf16 stores
  float* xw = (float*)s_mem + wave*2176;
  __bf16* tpw = tp + ((size_t)b*S_ + qt*16)*S_ + wave*256;
  #pragma unroll
  for (int h = 0; h < 2; ++h) {
    #pragma unroll
    for (int j = 0; j < 8; ++j)
      *(f32x4*)(xw + l15*136 + j*16 + lhi*4) = sc[h*8 + j];
    bar_lds();
    #pragma unroll
    for (int rr = 0; rr < 8; ++rr) {
      int r = rr*2 + (lane >> 5);
      f32x4 a = *(f32x4*)(xw + r*136 + (lane & 31)*4);
      bf16x4 o;
      o[0]=(__bf16)a[0]; o[1]=(__bf16)a[1]; o[2]=(__bf16)a[2]; o[3]=(__bf16)a[3];
      *(bf16x4*)(tpw + (size_t)r*S_ + h*128 + (lane & 31)*4) = o;
    }
    bar_lds();
  }
}

// ---------------- attn (R13 best): non-swapped QK^T -> swizzled LDS scores ----------------
// -> per-row softmax from LDS -> coalesced pa -> P bf16 LDS -> PV with global Vt
__global__ __launch_bounds__(256) void attn_kernel(
    const float* __restrict__ Q, const __bf16* __restrict__ Kb,
    const __bf16* __restrict__ Vt, const __bf16* __restrict__ tp,
    float* __restrict__ out, float* __restrict__ pa)
{
  int bid0 = blockIdx.x;                 // 4096 = 8 * 512
  int bid = (bid0 & 7)*512 + (bid0 >> 3);
  int qt = bid & 63;
  int h  = (bid >> 6) & 15;
  int b  = bid >> 10;
  int tid = threadIdx.x, wave = tid >> 6, lane = tid & 63;
  int l15 = lane & 15, lhi = lane >> 4;

  // scores/P bf16 [16][1024], XOR-swizzled: byte = row*2048 + ((col*2) ^ ((row&7)<<4))
  __shared__ __align__(16) char s_p[16*2048];

  size_t bh = (size_t)b*H_ + h;
  const __bf16* Kbh = Kb + bh*S_*D_;
  const __bf16* tpb = tp + ((size_t)b*S_ + qt*16)*S_;   // [16 rows][1024]

  // Q fragments (A): row = l15 (q), k(d) = dc*32 + lhi*8 + i
  bf16x8 qf[2];
  #pragma unroll
  for (int dc = 0; dc < 2; ++dc)
    qf[dc] = cvt8(Q + (bh*S_ + qt*16 + l15)*D_ + dc*32 + lhi*8);

  // ---- QK^T: wave w covers k in [w*256, w*256+256) ----
  for (int kt = 0; kt < 16; ++kt) {
    int kb = wave*256 + kt*16;
    int kcol = kb + l15;
    const __bf16* kr = Kbh + (size_t)kcol*D_ + lhi*8;
    bf16x8 k0 = *(const bf16x8*)kr;
    bf16x8 k1 = *(const bf16x8*)(kr + 32);
    f32x4 acc = {0.f,0.f,0.f,0.f};
    acc = MFMA16(qf[0], k0, acc);
    acc = MFMA16(qf[1], k1, acc);
    #pragma unroll
    for (int i = 0; i < 4; ++i) {
      int row = lhi*4 + i;                  // q within tile
      float t = (float)tpb[(size_t)row*S_ + kcol];
      float s = (t > 0.f) ? acc[i]*0.125f*t : NEGV*(-t);
      *(__bf16*)(s_p + row*2048 + ((kcol*2) ^ ((row&7)<<4))) = (__bf16)s;
    }
  }
  bar_lds();

  // ---- softmax: wave owns rows [wave*4, wave*4+4); pa written inline (coalesced) ----
  #pragma unroll
  for (int r = 0; r < 4; ++r) {
    int row = wave*4 + r;
    int swz = (row & 7) << 4;
    float sv[16]; float m = -3.4e38f;
    #pragma unroll
    for (int j = 0; j < 16; ++j) {
      sv[j] = (float)*(const __bf16*)(s_p + row*2048 + (((lane + j*64)*2) ^ swz));
      m = fmaxf(m, sv[j]);
    }
    #pragma unroll
    for (int o = 32; o >= 1; o >>= 1) m = fmaxf(m, __shfl_xor(m, o));
    float ev[16]; float sum = 0.f;
    #pragma unroll
    for (int j = 0; j < 16; ++j) { ev[j] = __expf(sv[j]-m); sum += ev[j]; }
    #pragma unroll
    for (int o = 32; o >= 1; o >>= 1) sum += __shfl_xor(sum, o);
    float inv = 1.0f/sum;
    float* par = pa + (bh*S_ + qt*16 + row)*S_;
    #pragma unroll
    for (int j = 0; j < 16; ++j) {
      float pv = ev[j]*inv;
      par[lane + j*64] = pv;                // coalesced 256B/instr
      *(__bf16*)(s_p + row*2048 + (((lane + j*64)*2) ^ swz)) = (__bf16)pv;
    }
  }
  bar_lds();

  // ---- PV: wave w covers d in [w*16, w*16+16); A from LDS, B from global Vt ----
  const __bf16* Vh = Vt + (bh*D_ + wave*16 + l15)*S_ + lhi*8;
  f32x4 oacc = {0.f,0.f,0.f,0.f};
  #pragma unroll 8
  for (int ks = 0; ks < 32; ++ks) {
    bf16x8 a  = *(const bf16x8*)(s_p + l15*2048 + ((ks*64 + lhi*16) ^ ((l15 & 7) << 4)));
    bf16x8 bv = *(const bf16x8*)(Vh + ks*32);
    oacc = MFMA16(a, bv, oacc);
  }
  #pragma unroll
  for (int i = 0; i < 4; ++i)
    out[(bh*S_ + qt*16 + lhi*4 + i)*D_ + wave*16 + l15] = oacc[i];
}

extern "C" void kernel_launch(void* const* d_in, const int* in_sizes, int n_in,
                              void* d_out, int out_size, void* d_ws, size_t ws_size,
                              hipStream_t stream) {
  const float* Q    = (const float*)d_in[0];
  const float* K    = (const float*)d_in[1];
  const float* V    = (const float*)d_in[2];
  const int*   mask = (const int*)d_in[4];
  const float* tq   = (const float*)d_in[5];
  const float* tk   = (const float*)d_in[6];

  // ws layout: tp bf16 [B,S,S] = 8MB | Kb bf16 [B,H,S,D] = 8MB | Vt bf16 [B,H,D,S] = 8MB
  __bf16* tp = (__bf16*)d_ws;
  __bf16* Kb = tp + (size_t)B_*S_*S_;
  __bf16* Vt = Kb + (size_t)B_*H_*S_*D_;

  float* outp = (float*)d_out;                      // [B,H,S,D]
  float* pa   = outp + (size_t)B_*H_*S_*D_;         // [B,H,S,S]

  prep_kernel <<<B_*H_*16, 256, 0, stream>>>(K, V, Kb, Vt);
  topic_kernel<<<B_*64,    256, 0, stream>>>(tq, tk, mask, tp);
  attn_kernel <<<B_*H_*64, 256, 0, stream>>>(Q, Kb, Vt, tp, outp, pa);
}